// Round 7
// baseline (883.304 us; speedup 1.0000x reference)
//
#include <hip/hip_runtime.h>
#include <math.h>

#define NN 50000      // nodes
#define NE 800000     // edges
#define NP 200000     // link pairs
#define NF 128        // feature dim
#define NEDGE_TOT (NE + NN)   // edges + self loops
#define NBLK 196              // ceil(NN/256)

typedef __attribute__((ext_vector_type(8))) short short8;
typedef __attribute__((ext_vector_type(4))) float float4v;

// ---- bf16 helpers (manual, RNE) ----
__device__ __forceinline__ float bf_lo(unsigned u) { return __uint_as_float(u << 16); }
__device__ __forceinline__ float bf_hi(unsigned u) { return __uint_as_float(u & 0xffff0000u); }
__device__ __forceinline__ unsigned short f2bf(float f) {
    unsigned u = __float_as_uint(f);
    return (unsigned short)((u + 0x7fffu + ((u >> 16) & 1u)) >> 16);
}
__device__ __forceinline__ unsigned pack2bf(float a, float b) {
    return (unsigned)f2bf(a) | ((unsigned)f2bf(b) << 16);
}

// ---------------------------------------------------------------------------
// CSR build
// ---------------------------------------------------------------------------
__global__ __launch_bounds__(256) void init_cnt_k(int* __restrict__ cnt) {
    int i = blockIdx.x * 256 + threadIdx.x;
    if (i < NN) cnt[i] = 1;  // self-loop
}

__global__ __launch_bounds__(256) void count_k(const int* __restrict__ ei,
                                               int* __restrict__ cnt) {
    int e = blockIdx.x * 256 + threadIdx.x;
    if (e < NE) atomicAdd(&cnt[ei[NE + e]], 1);
}

// reduce + fused dinv
__global__ __launch_bounds__(256) void scan_reduce_k(const int* __restrict__ cnt,
                                                     int* __restrict__ bsum,
                                                     float* __restrict__ dinv) {
    __shared__ int s[256];
    int t = threadIdx.x;
    int idx = blockIdx.x * 256 + t;
    int v = (idx < NN) ? cnt[idx] : 0;
    if (idx < NN) dinv[idx] = rsqrtf((float)v);
    s[t] = v;
    __syncthreads();
    for (int off = 128; off > 0; off >>= 1) {
        if (t < off) s[t] += s[t + off];
        __syncthreads();
    }
    if (t == 0) bsum[blockIdx.x] = s[0];
}

__global__ __launch_bounds__(256) void scan_bsums_k(const int* __restrict__ bsum,
                                                    int* __restrict__ boff) {
    __shared__ int s[256];
    int t = threadIdx.x;
    int v = (t < NBLK) ? bsum[t] : 0;
    s[t] = v;
    __syncthreads();
    for (int off = 1; off < 256; off <<= 1) {
        int add = (t >= off) ? s[t - off] : 0;
        __syncthreads();
        s[t] += add;
        __syncthreads();
    }
    if (t < NBLK) boff[t] = s[t] - v;
}

__global__ __launch_bounds__(256) void scan_down_k(const int* __restrict__ cnt,
                                                   const int* __restrict__ boff,
                                                   int* __restrict__ row_ptr,
                                                   int* __restrict__ wptr) {
    __shared__ int s[256];
    int t = threadIdx.x;
    int idx = blockIdx.x * 256 + t;
    int v = (idx < NN) ? cnt[idx] : 0;
    s[t] = v;
    __syncthreads();
    for (int off = 1; off < 256; off <<= 1) {
        int add = (t >= off) ? s[t - off] : 0;
        __syncthreads();
        s[t] += add;
        __syncthreads();
    }
    int excl = s[t] - v + boff[blockIdx.x];
    if (idx < NN) {
        row_ptr[idx] = excl;
        wptr[idx] = excl;
        if (idx == NN - 1) row_ptr[NN] = excl + v;
    }
}

// 4 B records: just the source column (norm folded into hs scaling)
__global__ __launch_bounds__(256) void scatter_k(const int* __restrict__ ei,
                                                 int* __restrict__ wptr,
                                                 int* __restrict__ cols) {
    int e = blockIdx.x * 256 + threadIdx.x;
    if (e >= NEDGE_TOT) return;
    int s, d;
    if (e < NE) { s = ei[e]; d = ei[NE + e]; }
    else        { s = d = e - NE; }
    int pos = atomicAdd(&wptr[d], 1);
    cols[pos] = s;
}

// zero row NN (the dummy-gather row) of the four hs buffers
__global__ __launch_bounds__(256) void zero_k(unsigned short* Ys1, unsigned short* Ys2,
                                              unsigned short* HA, unsigned short* HB) {
    int t = threadIdx.x;  // 256 threads; 4 rows x 64 uints
    unsigned short* bufs[4] = {Ys1, Ys2, HA, HB};
    unsigned short* b = bufs[t >> 6];
    ((unsigned*)(b + (size_t)NN * NF))[t & 63] = 0u;
}

// W fp32 -> bf16 row-major
__global__ __launch_bounds__(256) void cast_w_k(const float* __restrict__ W,
                                                unsigned short* __restrict__ Wb) {
    int t = blockIdx.x * 256 + threadIdx.x;
    if (t >= 128 * 128 / 8) return;
    int i = t * 8;
    float4 f0 = *(const float4*)(W + i);
    float4 f1 = *(const float4*)(W + i + 4);
    uint4 q;
    q.x = pack2bf(f0.x, f0.y);
    q.y = pack2bf(f0.z, f0.w);
    q.z = pack2bf(f1.x, f1.y);
    q.w = pack2bf(f1.z, f1.w);
    *(uint4*)(Wb + i) = q;
}

// ---------------------------------------------------------------------------
// MFMA GEMM (verified fragment layouts, rounds 2-6): Y = X @ W.T + b.
// F32IN: X fp32 (layer 1, reads input x directly); else bf16 row-major.
// Dual epilogue: Yu = unscaled bf16 (the x0 stream), Ys = dinv[row]-scaled hs0.
// LDS transpose (pad 136) -> vectorized uint4 stores.
// ---------------------------------------------------------------------------
#define GPAD 136
template <bool F32IN>
__global__ __launch_bounds__(256) void gemm_mfma_k(const void* __restrict__ Xv,
                                                   const unsigned short* __restrict__ Wb,
                                                   const float* __restrict__ bias,
                                                   const float* __restrict__ dinv,
                                                   unsigned short* __restrict__ Yu,
                                                   unsigned short* __restrict__ Ys,
                                                   int nrows) {
    __shared__ unsigned short sm[4 * 16 * GPAD];  // 17408 B
    int wave = threadIdx.x >> 6, lane = threadIdx.x & 63;
    int rbase = blockIdx.x * 64 + wave * 16;
    if (rbase >= nrows) return;
    int quad = lane >> 4, mn = lane & 15;
    float4v acc[8];
#pragma unroll
    for (int ft = 0; ft < 8; ++ft) acc[ft] = (float4v){0.f, 0.f, 0.f, 0.f};
#pragma unroll
    for (int kb = 0; kb < 128; kb += 32) {
        short8 a;
        if (F32IN) {
            const float* X = (const float*)Xv;
            float4 f0 = *(const float4*)(X + (size_t)(rbase + mn) * NF + kb + quad * 8);
            float4 f1 = *(const float4*)(X + (size_t)(rbase + mn) * NF + kb + quad * 8 + 4);
            a[0] = (short)f2bf(f0.x); a[1] = (short)f2bf(f0.y);
            a[2] = (short)f2bf(f0.z); a[3] = (short)f2bf(f0.w);
            a[4] = (short)f2bf(f1.x); a[5] = (short)f2bf(f1.y);
            a[6] = (short)f2bf(f1.z); a[7] = (short)f2bf(f1.w);
        } else {
            const unsigned short* X = (const unsigned short*)Xv;
            a = *(const short8*)(X + (size_t)(rbase + mn) * NF + kb + quad * 8);
        }
#pragma unroll
        for (int ft = 0; ft < 8; ++ft) {
            short8 b = *(const short8*)(Wb + (size_t)(ft * 16 + mn) * NF + kb + quad * 8);
            acc[ft] = __builtin_amdgcn_mfma_f32_16x16x32_bf16(a, b, acc[ft], 0, 0, 0);
        }
    }
    unsigned short* smw = sm + wave * 16 * GPAD;
#pragma unroll
    for (int ft = 0; ft < 8; ++ft) {
        float bv = bias[ft * 16 + mn];
#pragma unroll
        for (int r = 0; r < 4; ++r)
            smw[(quad * 4 + r) * GPAD + ft * 16 + mn] = f2bf(acc[ft][r] + bv);
    }
    __syncthreads();
#pragma unroll
    for (int t = 0; t < 4; ++t) {
        int rl = t * 4 + quad;
        int row = rbase + rl;
        uint4 q = *(const uint4*)(smw + rl * GPAD + mn * 8);
        *(uint4*)(Yu + (size_t)row * NF + mn * 8) = q;
        float g = dinv[row];
        uint4 qs;
        qs.x = pack2bf(g * bf_lo(q.x), g * bf_hi(q.x));
        qs.y = pack2bf(g * bf_lo(q.y), g * bf_hi(q.y));
        qs.z = pack2bf(g * bf_lo(q.z), g * bf_hi(q.z));
        qs.w = pack2bf(g * bf_lo(q.w), g * bf_hi(q.w));
        *(uint4*)(Ys + (size_t)row * NF + mn * 8) = qs;
    }
}

// ---------------------------------------------------------------------------
// APPNP step on scaled state hs[v] = dinv[v]*h[v]:
//   A = sum_{e in row v} hs[col_e]          (plain adds, NO per-edge weight)
//   h_new = 0.9*dinv[v]*A + 0.1*x0[v]
//   mode 0: out[v] = dinv[v]*h_new (bf16)   mode 1: out[v] = relu(h_new)
//   mode 2: relu + fused pair-head projection -> puv
// One 64-lane wave per node; uint2/lane, 2 edges per 512 B gather instr;
// unguarded 8-edge batches (4 independent loads); OOB tail lanes carry
// col = NN, a zeroed dummy row. Single shfl_xor(32) merge.
// ---------------------------------------------------------------------------
__global__ __launch_bounds__(256) void appnp_s_k(const unsigned short* __restrict__ hs,
                                                 const unsigned short* __restrict__ x0,
                                                 const float* __restrict__ dinv,
                                                 unsigned short* __restrict__ out,
                                                 const int* __restrict__ row_ptr,
                                                 const int* __restrict__ cols,
                                                 int mode,
                                                 const float* __restrict__ W3,
                                                 float4* __restrict__ puv) {
    int wid = (blockIdx.x * 256 + threadIdx.x) >> 6;
    int lane = threadIdx.x & 63;
    if (wid >= NN) return;
    int half = lane >> 5, li = lane & 31;
    int beg = row_ptr[wid], end = row_ptr[wid + 1];
    float a0 = 0.f, a1 = 0.f, a2 = 0.f, a3 = 0.f;
    for (int e = beg; e < end; e += 64) {
        int m = end - e;
        if (m > 64) m = 64;
        int c = (lane < m) ? cols[e + lane] : NN;  // NN = zero row
        int j = 0;
        for (; j + 8 <= m; j += 8) {
            int c0 = __shfl(c, j + half, 64);
            int c1 = __shfl(c, j + 2 + half, 64);
            int c2 = __shfl(c, j + 4 + half, 64);
            int c3 = __shfl(c, j + 6 + half, 64);
            uint2 q0 = *((const uint2*)(hs + (size_t)c0 * NF) + li);
            uint2 q1 = *((const uint2*)(hs + (size_t)c1 * NF) + li);
            uint2 q2 = *((const uint2*)(hs + (size_t)c2 * NF) + li);
            uint2 q3 = *((const uint2*)(hs + (size_t)c3 * NF) + li);
            a0 += (bf_lo(q0.x) + bf_lo(q1.x)) + (bf_lo(q2.x) + bf_lo(q3.x));
            a1 += (bf_hi(q0.x) + bf_hi(q1.x)) + (bf_hi(q2.x) + bf_hi(q3.x));
            a2 += (bf_lo(q0.y) + bf_lo(q1.y)) + (bf_lo(q2.y) + bf_lo(q3.y));
            a3 += (bf_hi(q0.y) + bf_hi(q1.y)) + (bf_hi(q2.y) + bf_hi(q3.y));
        }
        for (; j < m; j += 2) {
            int cj = __shfl(c, j + half, 64);   // src >= m -> c = NN (zero row)
            uint2 q = *((const uint2*)(hs + (size_t)cj * NF) + li);
            a0 += bf_lo(q.x);
            a1 += bf_hi(q.x);
            a2 += bf_lo(q.y);
            a3 += bf_hi(q.y);
        }
    }
    a0 += __shfl_xor(a0, 32, 64);
    a1 += __shfl_xor(a1, 32, 64);
    a2 += __shfl_xor(a2, 32, 64);
    a3 += __shfl_xor(a3, 32, 64);
    if (half == 0) {
        float g = dinv[wid];
        float s9 = 0.9f * g;
        uint2 xq = *((const uint2*)(x0 + (size_t)wid * NF) + li);
        float h0 = s9 * a0 + 0.1f * bf_lo(xq.x);
        float h1 = s9 * a1 + 0.1f * bf_hi(xq.x);
        float h2 = s9 * a2 + 0.1f * bf_lo(xq.y);
        float h3 = s9 * a3 + 0.1f * bf_hi(xq.y);
        if (mode == 0) {
            uint2 oq;
            oq.x = pack2bf(g * h0, g * h1);
            oq.y = pack2bf(g * h2, g * h3);
            *((uint2*)(out + (size_t)wid * NF) + li) = oq;
        } else {
            h0 = fmaxf(h0, 0.f); h1 = fmaxf(h1, 0.f);
            h2 = fmaxf(h2, 0.f); h3 = fmaxf(h3, 0.f);
            if (mode == 1) {
                uint2 oq;
                oq.x = pack2bf(h0, h1);
                oq.y = pack2bf(h2, h3);
                *((uint2*)(out + (size_t)wid * NF) + li) = oq;
            } else {
                int fb = li * 4;
                float4 wu0 = *(const float4*)(W3 + fb);
                float4 wv0 = *(const float4*)(W3 + 128 + fb);
                float4 wu1 = *(const float4*)(W3 + 256 + fb);
                float4 wv1 = *(const float4*)(W3 + 384 + fb);
                float du0 = h0 * wu0.x + h1 * wu0.y + h2 * wu0.z + h3 * wu0.w;
                float du1 = h0 * wu1.x + h1 * wu1.y + h2 * wu1.z + h3 * wu1.w;
                float dv0 = h0 * wv0.x + h1 * wv0.y + h2 * wv0.z + h3 * wv0.w;
                float dv1 = h0 * wv1.x + h1 * wv1.y + h2 * wv1.z + h3 * wv1.w;
#pragma unroll
                for (int off = 1; off < 32; off <<= 1) {
                    du0 += __shfl_xor(du0, off, 64);
                    du1 += __shfl_xor(du1, off, 64);
                    dv0 += __shfl_xor(dv0, off, 64);
                    dv1 += __shfl_xor(dv1, off, 64);
                }
                if (li == 0) puv[wid] = make_float4(du0, du1, dv0, dv1);
            }
        }
    }
}

// ---------------------------------------------------------------------------
// Pair head from precomputed projections: one thread per pair.
// ---------------------------------------------------------------------------
__global__ __launch_bounds__(256) void pair2_k(const float4* __restrict__ puv,
                                               const int2* __restrict__ index,
                                               const float* __restrict__ b3,
                                               float* __restrict__ outp) {
    int p = blockIdx.x * 256 + threadIdx.x;
    if (p >= NP) return;
    int2 uv = index[p];
    float4 a = puv[uv.x];
    float4 b = puv[uv.y];
    float s0 = a.x + b.z + b3[0];
    float s1 = a.y + b.w + b3[1];
    float m = fmaxf(s0, s1);
    float lse = m + logf(expf(s0 - m) + expf(s1 - m));
    *(float2*)(outp + (size_t)p * 2) = make_float2(s0 - lse, s1 - lse);
}

// ---------------------------------------------------------------------------
// Launch
// ---------------------------------------------------------------------------
extern "C" void kernel_launch(void* const* d_in, const int* in_sizes, int n_in,
                              void* d_out, int out_size, void* d_ws, size_t ws_size,
                              hipStream_t stream) {
    const float* x  = (const float*)d_in[0];
    const int* ei   = (const int*)d_in[1];
    const int* idx  = (const int*)d_in[2];
    const float* W1 = (const float*)d_in[3];
    const float* b1 = (const float*)d_in[4];
    const float* W2 = (const float*)d_in[5];
    const float* b2 = (const float*)d_in[6];
    const float* W3 = (const float*)d_in[7];
    const float* b3 = (const float*)d_in[8];
    float* out = (float*)d_out;

    char* ws = (char*)d_ws;
    size_t off = 0;
    auto alloc = [&](size_t bytes) -> void* {
        void* p = ws + off;
        off = (off + bytes + 255) & ~(size_t)255;
        return p;
    };
    const size_t HROWS = (size_t)(NN + 1) * NF;  // +1: zero dummy row
    int*   cnt     = (int*)  alloc(NN * sizeof(int));
    float* dinv    = (float*)alloc(NN * sizeof(float));
    int*   row_ptr = (int*)  alloc((NN + 1) * sizeof(int));
    int*   wptr    = (int*)  alloc(NN * sizeof(int));
    int*   bsum    = (int*)  alloc(NBLK * sizeof(int));
    int*   boff    = (int*)  alloc(NBLK * sizeof(int));
    int*   cols    = (int*)  alloc((size_t)NEDGE_TOT * sizeof(int));
    float4* puv    = (float4*)alloc((size_t)NN * sizeof(float4));
    unsigned short* Wb1 = (unsigned short*)alloc(128 * 128 * 2);
    unsigned short* Wb2 = (unsigned short*)alloc(128 * 128 * 2);
    unsigned short* Yu1 = (unsigned short*)alloc(HROWS * 2);
    unsigned short* Ys1 = (unsigned short*)alloc(HROWS * 2);
    unsigned short* Yu2 = (unsigned short*)alloc(HROWS * 2);
    unsigned short* Ys2 = (unsigned short*)alloc(HROWS * 2);
    unsigned short* HA  = (unsigned short*)alloc(HROWS * 2);
    unsigned short* HB  = (unsigned short*)alloc(HROWS * 2);
    unsigned short* Hrelu = (unsigned short*)alloc((size_t)NN * NF * 2);

    const int gN    = (NN + 255) / 256;
    const int gE    = (NE + 255) / 256;
    const int gET   = (NEDGE_TOT + 255) / 256;
    const int gGemm = (NN + 63) / 64;            // wave per 16 rows
    const int gStep = (NN * 64 + 255) / 256;     // 64-lane wave per node
    const int gPair = (NP + 255) / 256;          // thread per pair

    // ---- weights + gcn_norm + CSR ----
    cast_w_k<<<8, 256, 0, stream>>>(W1, Wb1);
    cast_w_k<<<8, 256, 0, stream>>>(W2, Wb2);
    init_cnt_k<<<gN, 256, 0, stream>>>(cnt);
    count_k<<<gE, 256, 0, stream>>>(ei, cnt);
    scan_reduce_k<<<NBLK, 256, 0, stream>>>(cnt, bsum, dinv);
    scan_bsums_k<<<1, 256, 0, stream>>>(bsum, boff);
    scan_down_k<<<NBLK, 256, 0, stream>>>(cnt, boff, row_ptr, wptr);
    scatter_k<<<gET, 256, 0, stream>>>(ei, wptr, cols);
    zero_k<<<1, 256, 0, stream>>>(Ys1, Ys2, HA, HB);

    // ---- layer 1 ----
    gemm_mfma_k<true><<<gGemm, 256, 0, stream>>>(x, Wb1, b1, dinv, Yu1, Ys1, NN);
    {
        const unsigned short* cur = Ys1;
        for (int k = 0; k < 10; ++k) {
            unsigned short* dst = (k == 9) ? Hrelu : ((k & 1) ? HB : HA);
            appnp_s_k<<<gStep, 256, 0, stream>>>(cur, Yu1, dinv, dst, row_ptr,
                                                 cols, (k == 9) ? 1 : 0, W3, puv);
            cur = dst;
        }
    }
    // ---- layer 2 ----
    gemm_mfma_k<false><<<gGemm, 256, 0, stream>>>(Hrelu, Wb2, b2, dinv, Yu2, Ys2, NN);
    {
        const unsigned short* cur = Ys2;
        for (int k = 0; k < 10; ++k) {
            unsigned short* dst = (k & 1) ? HB : HA;
            appnp_s_k<<<gStep, 256, 0, stream>>>(cur, Yu2, dinv, dst, row_ptr,
                                                 cols, (k == 9) ? 2 : 0, W3, puv);
            cur = dst;
        }
    }
    // ---- pair head ----
    pair2_k<<<gPair, 256, 0, stream>>>(puv, (const int2*)idx, b3, out);
}

// Round 8
// 832.335 us; speedup vs baseline: 1.0612x; 1.0612x over previous
//
#include <hip/hip_runtime.h>
#include <math.h>

#define NN 50000      // nodes
#define NE 800000     // edges
#define NP 200000     // link pairs
#define NF 128        // feature dim
#define NEDGE_TOT (NE + NN)   // edges + self loops
#define NBLK 196              // ceil(NN/256)
#define NBK 64                // dst-range buckets
#define DPB 782               // dsts per bucket (64*782 = 50048 >= NN)
#define BKCAP 16384           // bucket capacity (avg 13281, sigma ~114 -> +27 sigma)
#define EPB 2048              // edges per Phase-A block

typedef __attribute__((ext_vector_type(8))) short short8;
typedef __attribute__((ext_vector_type(4))) float float4v;

// ---- bf16 helpers (manual, RNE) ----
__device__ __forceinline__ float bf_lo(unsigned u) { return __uint_as_float(u << 16); }
__device__ __forceinline__ float bf_hi(unsigned u) { return __uint_as_float(u & 0xffff0000u); }
__device__ __forceinline__ unsigned short f2bf(float f) {
    unsigned u = __float_as_uint(f);
    return (unsigned short)((u + 0x7fffu + ((u >> 16) & 1u)) >> 16);
}
__device__ __forceinline__ unsigned pack2bf(float a, float b) {
    return (unsigned)f2bf(a) | ((unsigned)f2bf(b) << 16);
}

// ---------------------------------------------------------------------------
// degree count + scan (row_ptr, dinv)
// ---------------------------------------------------------------------------
__global__ __launch_bounds__(256) void init_cnt_k(int* __restrict__ cnt) {
    int i = blockIdx.x * 256 + threadIdx.x;
    if (i < NN) cnt[i] = 1;  // self-loop
}

__global__ __launch_bounds__(256) void count_k(const int* __restrict__ ei,
                                               int* __restrict__ cnt) {
    int e = blockIdx.x * 256 + threadIdx.x;
    if (e < NE) atomicAdd(&cnt[ei[NE + e]], 1);
}

__global__ __launch_bounds__(256) void scan_reduce_k(const int* __restrict__ cnt,
                                                     int* __restrict__ bsum,
                                                     float* __restrict__ dinv) {
    __shared__ int s[256];
    int t = threadIdx.x;
    int idx = blockIdx.x * 256 + t;
    int v = (idx < NN) ? cnt[idx] : 0;
    if (idx < NN) dinv[idx] = rsqrtf((float)v);
    s[t] = v;
    __syncthreads();
    for (int off = 128; off > 0; off >>= 1) {
        if (t < off) s[t] += s[t + off];
        __syncthreads();
    }
    if (t == 0) bsum[blockIdx.x] = s[0];
}

__global__ __launch_bounds__(256) void scan_bsums_k(const int* __restrict__ bsum,
                                                    int* __restrict__ boff) {
    __shared__ int s[256];
    int t = threadIdx.x;
    int v = (t < NBLK) ? bsum[t] : 0;
    s[t] = v;
    __syncthreads();
    for (int off = 1; off < 256; off <<= 1) {
        int add = (t >= off) ? s[t - off] : 0;
        __syncthreads();
        s[t] += add;
        __syncthreads();
    }
    if (t < NBLK) boff[t] = s[t] - v;
}

__global__ __launch_bounds__(256) void scan_down_k(const int* __restrict__ cnt,
                                                   const int* __restrict__ boff,
                                                   int* __restrict__ row_ptr) {
    __shared__ int s[256];
    int t = threadIdx.x;
    int idx = blockIdx.x * 256 + t;
    int v = (idx < NN) ? cnt[idx] : 0;
    s[t] = v;
    __syncthreads();
    for (int off = 1; off < 256; off <<= 1) {
        int add = (t >= off) ? s[t - off] : 0;
        __syncthreads();
        s[t] += add;
        __syncthreads();
    }
    int excl = s[t] - v + boff[blockIdx.x];
    if (idx < NN) {
        row_ptr[idx] = excl;
        if (idx == NN - 1) row_ptr[NN] = excl + v;
    }
}

// ---------------------------------------------------------------------------
// Two-phase binned CSR build.
// Phase A: bin edges into 64 dst-range buckets. Each block stages its 2048
// edges bucket-major in LDS, reserves one contiguous global chunk per bucket
// (one atomic), flushes chunks (block-exclusive -> full-line writes).
// ---------------------------------------------------------------------------
__global__ __launch_bounds__(256) void bin_k(const int* __restrict__ ei,
                                             int* __restrict__ gtail,
                                             int2* __restrict__ gbk) {
    __shared__ int cntA[NBK], baseA[NBK], gposA[NBK];
    __shared__ int2 stage[EPB];
    int tid = threadIdx.x;
    int ebase = blockIdx.x * EPB;
    int sv[8], dv[8], lp8[8], bk8[8];
    bool val[8];
    if (tid < NBK) cntA[tid] = 0;
    __syncthreads();
#pragma unroll
    for (int k = 0; k < 8; ++k) {
        int e = ebase + k * 256 + tid;
        val[k] = (e < NEDGE_TOT);
        if (val[k]) {
            int s, d;
            if (e < NE) { s = ei[e]; d = ei[NE + e]; }
            else        { s = d = e - NE; }
            sv[k] = s; dv[k] = d;
            bk8[k] = d / DPB;
            lp8[k] = atomicAdd(&cntA[bk8[k]], 1);
        }
    }
    __syncthreads();
    if (tid == 0) {
        int run = 0;
        for (int b = 0; b < NBK; ++b) { baseA[b] = run; run += cntA[b]; }
    }
    __syncthreads();
    if (tid < NBK && cntA[tid] > 0)
        gposA[tid] = atomicAdd(&gtail[tid], cntA[tid]);
    __syncthreads();
#pragma unroll
    for (int k = 0; k < 8; ++k)
        if (val[k]) {
            int2 r; r.x = sv[k]; r.y = dv[k];
            stage[baseA[bk8[k]] + lp8[k]] = r;
        }
    __syncthreads();
    int total = baseA[NBK - 1] + cntA[NBK - 1];
    for (int i = tid; i < total; i += 256) {
        int2 r = stage[i];
        int b = r.y / DPB;
        gbk[(size_t)b * BKCAP + gposA[b] + (i - baseA[b])] = r;
    }
}

// Phase B: 64 blocks; block b exclusively owns dst range [b*DPB,(b+1)*DPB).
// LDS write-cursors from row_ptr; scatter records into its private contiguous
// cols region (single-writer -> full-line writebacks).
__global__ __launch_bounds__(256) void build_k(const int* __restrict__ row_ptr,
                                               const int* __restrict__ gtail,
                                               const int2* __restrict__ gbk,
                                               int* __restrict__ cols) {
    __shared__ int wcur[DPB];
    int tid = threadIdx.x;
    int b = blockIdx.x;
    int d0 = b * DPB;
    for (int i = tid; i < DPB; i += 256) {
        int d = d0 + i;
        wcur[i] = (d < NN) ? row_ptr[d] : 0;
    }
    __syncthreads();
    int nb = gtail[b];
    const int2* src = gbk + (size_t)b * BKCAP;
    for (int t = tid; t < nb; t += 256) {
        int2 r = src[t];
        int pos = atomicAdd(&wcur[r.y - d0], 1);
        cols[pos] = r.x;
    }
}

// zero dummy rows of the four hs buffers + bucket tails
__global__ __launch_bounds__(256) void zero_k(unsigned short* Ys1, unsigned short* Ys2,
                                              unsigned short* HA, unsigned short* HB,
                                              int* gtail) {
    int t = threadIdx.x;  // 256 threads; 4 rows x 64 uints
    unsigned short* bufs[4] = {Ys1, Ys2, HA, HB};
    unsigned short* b = bufs[t >> 6];
    ((unsigned*)(b + (size_t)NN * NF))[t & 63] = 0u;
    if (t < NBK) gtail[t] = 0;
}

// W fp32 -> bf16 row-major
__global__ __launch_bounds__(256) void cast_w_k(const float* __restrict__ W,
                                                unsigned short* __restrict__ Wb) {
    int t = blockIdx.x * 256 + threadIdx.x;
    if (t >= 128 * 128 / 8) return;
    int i = t * 8;
    float4 f0 = *(const float4*)(W + i);
    float4 f1 = *(const float4*)(W + i + 4);
    uint4 q;
    q.x = pack2bf(f0.x, f0.y);
    q.y = pack2bf(f0.z, f0.w);
    q.z = pack2bf(f1.x, f1.y);
    q.w = pack2bf(f1.z, f1.w);
    *(uint4*)(Wb + i) = q;
}

// ---------------------------------------------------------------------------
// MFMA GEMM (verified fragment layouts, rounds 2-7): Y = X @ W.T + b.
// Dual epilogue: Yu = unscaled bf16 (x0 stream), Ys = dinv[row]-scaled hs0.
// ---------------------------------------------------------------------------
#define GPAD 136
template <bool F32IN>
__global__ __launch_bounds__(256) void gemm_mfma_k(const void* __restrict__ Xv,
                                                   const unsigned short* __restrict__ Wb,
                                                   const float* __restrict__ bias,
                                                   const float* __restrict__ dinv,
                                                   unsigned short* __restrict__ Yu,
                                                   unsigned short* __restrict__ Ys,
                                                   int nrows) {
    __shared__ unsigned short sm[4 * 16 * GPAD];  // 17408 B
    int wave = threadIdx.x >> 6, lane = threadIdx.x & 63;
    int rbase = blockIdx.x * 64 + wave * 16;
    if (rbase >= nrows) return;
    int quad = lane >> 4, mn = lane & 15;
    float4v acc[8];
#pragma unroll
    for (int ft = 0; ft < 8; ++ft) acc[ft] = (float4v){0.f, 0.f, 0.f, 0.f};
#pragma unroll
    for (int kb = 0; kb < 128; kb += 32) {
        short8 a;
        if (F32IN) {
            const float* X = (const float*)Xv;
            float4 f0 = *(const float4*)(X + (size_t)(rbase + mn) * NF + kb + quad * 8);
            float4 f1 = *(const float4*)(X + (size_t)(rbase + mn) * NF + kb + quad * 8 + 4);
            a[0] = (short)f2bf(f0.x); a[1] = (short)f2bf(f0.y);
            a[2] = (short)f2bf(f0.z); a[3] = (short)f2bf(f0.w);
            a[4] = (short)f2bf(f1.x); a[5] = (short)f2bf(f1.y);
            a[6] = (short)f2bf(f1.z); a[7] = (short)f2bf(f1.w);
        } else {
            const unsigned short* X = (const unsigned short*)Xv;
            a = *(const short8*)(X + (size_t)(rbase + mn) * NF + kb + quad * 8);
        }
#pragma unroll
        for (int ft = 0; ft < 8; ++ft) {
            short8 b = *(const short8*)(Wb + (size_t)(ft * 16 + mn) * NF + kb + quad * 8);
            acc[ft] = __builtin_amdgcn_mfma_f32_16x16x32_bf16(a, b, acc[ft], 0, 0, 0);
        }
    }
    unsigned short* smw = sm + wave * 16 * GPAD;
#pragma unroll
    for (int ft = 0; ft < 8; ++ft) {
        float bv = bias[ft * 16 + mn];
#pragma unroll
        for (int r = 0; r < 4; ++r)
            smw[(quad * 4 + r) * GPAD + ft * 16 + mn] = f2bf(acc[ft][r] + bv);
    }
    __syncthreads();
#pragma unroll
    for (int t = 0; t < 4; ++t) {
        int rl = t * 4 + quad;
        int row = rbase + rl;
        uint4 q = *(const uint4*)(smw + rl * GPAD + mn * 8);
        *(uint4*)(Yu + (size_t)row * NF + mn * 8) = q;
        float g = dinv[row];
        uint4 qs;
        qs.x = pack2bf(g * bf_lo(q.x), g * bf_hi(q.x));
        qs.y = pack2bf(g * bf_lo(q.y), g * bf_hi(q.y));
        qs.z = pack2bf(g * bf_lo(q.z), g * bf_hi(q.z));
        qs.w = pack2bf(g * bf_lo(q.w), g * bf_hi(q.w));
        *(uint4*)(Ys + (size_t)row * NF + mn * 8) = qs;
    }
}

// ---------------------------------------------------------------------------
// APPNP step on scaled state hs[v] = dinv[v]*h[v]:
//   A = sum_{e in row v} hs[col_e]  ;  h_new = 0.9*dinv[v]*A + 0.1*x0[v]
//   mode 0: out = dinv*h_new  | mode 1: out = relu(h_new) | mode 2: relu+proj
// One 64-lane wave per node; uint2/lane, 2 edges per 512 B gather instr;
// fixed 8-edge round-up batches (round-2's best-measured shape) — dummy
// slots gather the hot zeroed row NN. Single shfl_xor(32) merge.
// ---------------------------------------------------------------------------
__global__ __launch_bounds__(256) void appnp_s_k(const unsigned short* __restrict__ hs,
                                                 const unsigned short* __restrict__ x0,
                                                 const float* __restrict__ dinv,
                                                 unsigned short* __restrict__ out,
                                                 const int* __restrict__ row_ptr,
                                                 const int* __restrict__ cols,
                                                 int mode,
                                                 const float* __restrict__ W3,
                                                 float4* __restrict__ puv) {
    int wid = (blockIdx.x * 256 + threadIdx.x) >> 6;
    int lane = threadIdx.x & 63;
    if (wid >= NN) return;
    int half = lane >> 5, li = lane & 31;
    int beg = row_ptr[wid], end = row_ptr[wid + 1];
    float a0 = 0.f, a1 = 0.f, a2 = 0.f, a3 = 0.f;
    for (int e = beg; e < end; e += 64) {
        int m = end - e;
        if (m > 64) m = 64;
        int c = (lane < m) ? cols[e + lane] : NN;  // NN = zero row
        for (int j = 0; j < m; j += 8) {
#pragma unroll
            for (int p = 0; p < 4; ++p) {
                int cj = __shfl(c, j + 2 * p + half, 64);
                uint2 q = *((const uint2*)(hs + (size_t)cj * NF) + li);
                a0 += bf_lo(q.x);
                a1 += bf_hi(q.x);
                a2 += bf_lo(q.y);
                a3 += bf_hi(q.y);
            }
        }
    }
    a0 += __shfl_xor(a0, 32, 64);
    a1 += __shfl_xor(a1, 32, 64);
    a2 += __shfl_xor(a2, 32, 64);
    a3 += __shfl_xor(a3, 32, 64);
    if (half == 0) {
        float g = dinv[wid];
        float s9 = 0.9f * g;
        uint2 xq = *((const uint2*)(x0 + (size_t)wid * NF) + li);
        float h0 = s9 * a0 + 0.1f * bf_lo(xq.x);
        float h1 = s9 * a1 + 0.1f * bf_hi(xq.x);
        float h2 = s9 * a2 + 0.1f * bf_lo(xq.y);
        float h3 = s9 * a3 + 0.1f * bf_hi(xq.y);
        if (mode == 0) {
            uint2 oq;
            oq.x = pack2bf(g * h0, g * h1);
            oq.y = pack2bf(g * h2, g * h3);
            *((uint2*)(out + (size_t)wid * NF) + li) = oq;
        } else {
            h0 = fmaxf(h0, 0.f); h1 = fmaxf(h1, 0.f);
            h2 = fmaxf(h2, 0.f); h3 = fmaxf(h3, 0.f);
            if (mode == 1) {
                uint2 oq;
                oq.x = pack2bf(h0, h1);
                oq.y = pack2bf(h2, h3);
                *((uint2*)(out + (size_t)wid * NF) + li) = oq;
            } else {
                int fb = li * 4;
                float4 wu0 = *(const float4*)(W3 + fb);
                float4 wv0 = *(const float4*)(W3 + 128 + fb);
                float4 wu1 = *(const float4*)(W3 + 256 + fb);
                float4 wv1 = *(const float4*)(W3 + 384 + fb);
                float du0 = h0 * wu0.x + h1 * wu0.y + h2 * wu0.z + h3 * wu0.w;
                float du1 = h0 * wu1.x + h1 * wu1.y + h2 * wu1.z + h3 * wu1.w;
                float dv0 = h0 * wv0.x + h1 * wv0.y + h2 * wv0.z + h3 * wv0.w;
                float dv1 = h0 * wv1.x + h1 * wv1.y + h2 * wv1.z + h3 * wv1.w;
#pragma unroll
                for (int off = 1; off < 32; off <<= 1) {
                    du0 += __shfl_xor(du0, off, 64);
                    du1 += __shfl_xor(du1, off, 64);
                    dv0 += __shfl_xor(dv0, off, 64);
                    dv1 += __shfl_xor(dv1, off, 64);
                }
                if (li == 0) puv[wid] = make_float4(du0, du1, dv0, dv1);
            }
        }
    }
}

// ---------------------------------------------------------------------------
// Pair head from precomputed projections: one thread per pair.
// ---------------------------------------------------------------------------
__global__ __launch_bounds__(256) void pair2_k(const float4* __restrict__ puv,
                                               const int2* __restrict__ index,
                                               const float* __restrict__ b3,
                                               float* __restrict__ outp) {
    int p = blockIdx.x * 256 + threadIdx.x;
    if (p >= NP) return;
    int2 uv = index[p];
    float4 a = puv[uv.x];
    float4 b = puv[uv.y];
    float s0 = a.x + b.z + b3[0];
    float s1 = a.y + b.w + b3[1];
    float m = fmaxf(s0, s1);
    float lse = m + logf(expf(s0 - m) + expf(s1 - m));
    *(float2*)(outp + (size_t)p * 2) = make_float2(s0 - lse, s1 - lse);
}

// ---------------------------------------------------------------------------
// Launch
// ---------------------------------------------------------------------------
extern "C" void kernel_launch(void* const* d_in, const int* in_sizes, int n_in,
                              void* d_out, int out_size, void* d_ws, size_t ws_size,
                              hipStream_t stream) {
    const float* x  = (const float*)d_in[0];
    const int* ei   = (const int*)d_in[1];
    const int* idx  = (const int*)d_in[2];
    const float* W1 = (const float*)d_in[3];
    const float* b1 = (const float*)d_in[4];
    const float* W2 = (const float*)d_in[5];
    const float* b2 = (const float*)d_in[6];
    const float* W3 = (const float*)d_in[7];
    const float* b3 = (const float*)d_in[8];
    float* out = (float*)d_out;

    char* ws = (char*)d_ws;
    size_t off = 0;
    auto alloc = [&](size_t bytes) -> void* {
        void* p = ws + off;
        off = (off + bytes + 255) & ~(size_t)255;
        return p;
    };
    const size_t HROWS = (size_t)(NN + 1) * NF;  // +1: zero dummy row
    int*   cnt     = (int*)  alloc(NN * sizeof(int));
    float* dinv    = (float*)alloc(NN * sizeof(float));
    int*   row_ptr = (int*)  alloc((NN + 1) * sizeof(int));
    int*   bsum    = (int*)  alloc(NBLK * sizeof(int));
    int*   boff    = (int*)  alloc(NBLK * sizeof(int));
    int*   gtail   = (int*)  alloc(NBK * sizeof(int));
    int2*  gbk     = (int2*) alloc((size_t)NBK * BKCAP * sizeof(int2));  // 8 MB
    int*   cols    = (int*)  alloc((size_t)NEDGE_TOT * sizeof(int));
    float4* puv    = (float4*)alloc((size_t)NN * sizeof(float4));
    unsigned short* Wb1 = (unsigned short*)alloc(128 * 128 * 2);
    unsigned short* Wb2 = (unsigned short*)alloc(128 * 128 * 2);
    unsigned short* Yu1 = (unsigned short*)alloc(HROWS * 2);
    unsigned short* Ys1 = (unsigned short*)alloc(HROWS * 2);
    unsigned short* Yu2 = (unsigned short*)alloc(HROWS * 2);
    unsigned short* Ys2 = (unsigned short*)alloc(HROWS * 2);
    unsigned short* HA  = (unsigned short*)alloc(HROWS * 2);
    unsigned short* HB  = (unsigned short*)alloc(HROWS * 2);
    unsigned short* Hrelu = (unsigned short*)alloc((size_t)NN * NF * 2);

    const int gN    = (NN + 255) / 256;
    const int gE    = (NE + 255) / 256;
    const int gBin  = (NEDGE_TOT + EPB - 1) / EPB;   // 416
    const int gGemm = (NN + 63) / 64;                // wave per 16 rows
    const int gStep = (NN * 64 + 255) / 256;         // 64-lane wave per node
    const int gPair = (NP + 255) / 256;              // thread per pair

    // ---- weights + gcn_norm + binned CSR ----
    cast_w_k<<<8, 256, 0, stream>>>(W1, Wb1);
    cast_w_k<<<8, 256, 0, stream>>>(W2, Wb2);
    zero_k<<<1, 256, 0, stream>>>(Ys1, Ys2, HA, HB, gtail);
    init_cnt_k<<<gN, 256, 0, stream>>>(cnt);
    count_k<<<gE, 256, 0, stream>>>(ei, cnt);
    scan_reduce_k<<<NBLK, 256, 0, stream>>>(cnt, bsum, dinv);
    scan_bsums_k<<<1, 256, 0, stream>>>(bsum, boff);
    scan_down_k<<<NBLK, 256, 0, stream>>>(cnt, boff, row_ptr);
    bin_k<<<gBin, 256, 0, stream>>>(ei, gtail, gbk);
    build_k<<<NBK, 256, 0, stream>>>(row_ptr, gtail, gbk, cols);

    // ---- layer 1 ----
    gemm_mfma_k<true><<<gGemm, 256, 0, stream>>>(x, Wb1, b1, dinv, Yu1, Ys1, NN);
    {
        const unsigned short* cur = Ys1;
        for (int k = 0; k < 10; ++k) {
            unsigned short* dst = (k == 9) ? Hrelu : ((k & 1) ? HB : HA);
            appnp_s_k<<<gStep, 256, 0, stream>>>(cur, Yu1, dinv, dst, row_ptr,
                                                 cols, (k == 9) ? 1 : 0, W3, puv);
            cur = dst;
        }
    }
    // ---- layer 2 ----
    gemm_mfma_k<false><<<gGemm, 256, 0, stream>>>(Hrelu, Wb2, b2, dinv, Yu2, Ys2, NN);
    {
        const unsigned short* cur = Ys2;
        for (int k = 0; k < 10; ++k) {
            unsigned short* dst = (k & 1) ? HB : HA;
            appnp_s_k<<<gStep, 256, 0, stream>>>(cur, Yu2, dinv, dst, row_ptr,
                                                 cols, (k == 9) ? 2 : 0, W3, puv);
            cur = dst;
        }
    }
    // ---- pair head ----
    pair2_k<<<gPair, 256, 0, stream>>>(puv, (const int2*)idx, b3, out);
}